// Round 7
// baseline (110.680 us; speedup 1.0000x reference)
//
#include <hip/hip_runtime.h>
#include <cmath>

// SE block: windowed mean-pool -> softsign(mW1+b1) -> sigmoid(softsign(hW2+b2)) -> gate x.
// B=32, M=2048, D=512, H=64, WIN=16 (M % WIN == 0, so reference edge-pad is a no-op).
// R6: R4 (best, 56.4us) with ONE change: phase-aliased LDS 33KB -> 12.8KB so 8 blocks/CU
//     fit (was 4). Keep R4's register-x source structure exactly — it keeps FETCH at
//     67MB (phase-4 remat loads hit L3); R5's explicit reload doubled FETCH to 132MB.
//     Aliasing lifetimes (all separated by existing barriers):
//       region A (8KB): s_ps [ph1..ph1b] | s_hp [ph2..ph2b] | s_gp [ph3..ph3b]
//       region B (4KB): s_m4 [ph1b..ph2] | s_g4 [ph3b..ph4]
//       s_h (512B) standalone.

constexpr int WIN = 16;
constexpr int D   = 512;
constexpr int H   = 64;
constexpr int TPB = 256;
constexpr int NW  = 2;                 // windows per block

__global__ __launch_bounds__(TPB, 8) void se_block_kernel(
    const float* __restrict__ x,
    const float* __restrict__ W1,
    const float* __restrict__ b1,
    const float* __restrict__ W2,
    const float* __restrict__ b2,
    float* __restrict__ y)
{
    const int tid = threadIdx.x;
    // Block handles NW consecutive windows: contiguous NW*WIN*D floats.
    const size_t base = (size_t)blockIdx.x * (size_t)(NW * WIN * D);
    const float4* __restrict__ xw = reinterpret_cast<const float4*>(x + base);
    float4*       __restrict__ yw = reinterpret_cast<float4*>(y + base);

    const float4* __restrict__ W1f4 = reinterpret_cast<const float4*>(W1); // [512] rows x 16 f4
    const float4* __restrict__ W2f4 = reinterpret_cast<const float4*>(W2); // [64] rows x 128 f4
    const float4* __restrict__ b2f4 = reinterpret_cast<const float4*>(b2);

    __shared__ __align__(16) char sA[NW * TPB * 16];      // 8 KB
    __shared__ __align__(16) char sB[NW * (D / 4) * 16];  // 4 KB
    __shared__ float s_h[NW][H];                          // 512 B

    float4* s_ps = reinterpret_cast<float4*>(sA);   // [NW][256]       ph1 -> ph1b
    float4* s_hp = reinterpret_cast<float4*>(sA);   // [16][NW][16]    ph2 -> ph2b
    float4* s_gp = reinterpret_cast<float4*>(sA);   // [2][NW][128]    ph3 -> ph3b
    float4* s_m4 = reinterpret_cast<float4*>(sB);   // [NW][128]       ph1b -> ph2
    float4* s_g4 = reinterpret_cast<float4*>(sB);   // [NW][128]       ph3b -> ph4

    // ---- Load x into registers. Window w, float4 element i*256+tid:
    //      col group c = tid&127, row = 2*i + (tid>>7).
    float4 r[NW][8];
#pragma unroll
    for (int w = 0; w < NW; ++w)
#pragma unroll
        for (int i = 0; i < 8; ++i) r[w][i] = xw[w * 2048 + i * TPB + tid];

    // ================= Phase 1: per-thread partial sums =================
#pragma unroll
    for (int w = 0; w < NW; ++w) {
        float4 ps = r[w][0];
#pragma unroll
        for (int i = 1; i < 8; ++i) {
            ps.x += r[w][i].x; ps.y += r[w][i].y; ps.z += r[w][i].z; ps.w += r[w][i].w;
        }
        s_ps[w * TPB + tid] = ps;
    }
    __syncthreads();

    // ================= Phase 1b: window means =================
    {   // 256 tasks = NW x 128 col-groups
        const int w = tid >> 7;
        const int c = tid & 127;
        const float4 a = s_ps[w * TPB + c];
        const float4 b = s_ps[w * TPB + c + 128];
        const float sc = 1.0f / 16.0f;
        float4 m;
        m.x = (a.x + b.x) * sc; m.y = (a.y + b.y) * sc;
        m.z = (a.z + b.z) * sc; m.w = (a.w + b.w) * sc;
        s_m4[w * 128 + c] = m;
    }
    __syncthreads();

    // ================= Phase 2: h_pre = m @ W1, 16-way k-split, batched over NW ========
    // Thread = (p = tid>>4 k-part, j4 = tid&15). k in [p*32, p*32+32).
    {
        const int p  = tid >> 4;
        const int j4 = tid & 15;
        float4 acc[NW];
#pragma unroll
        for (int w = 0; w < NW; ++w) acc[w] = make_float4(0.f, 0.f, 0.f, 0.f);
#pragma unroll 2
        for (int kk4 = 0; kk4 < 8; ++kk4) {
            const int c4 = p * 8 + kk4;                 // float4 group of k
            const int k  = c4 * 4;
            const float4 w0 = W1f4[(size_t)(k + 0) * 16 + j4];
            const float4 w1 = W1f4[(size_t)(k + 1) * 16 + j4];
            const float4 w2 = W1f4[(size_t)(k + 2) * 16 + j4];
            const float4 w3 = W1f4[(size_t)(k + 3) * 16 + j4];
#pragma unroll
            for (int w = 0; w < NW; ++w) {
                const float4 mv = s_m4[w * 128 + c4];
                acc[w].x = fmaf(mv.x, w0.x, acc[w].x); acc[w].y = fmaf(mv.x, w0.y, acc[w].y);
                acc[w].z = fmaf(mv.x, w0.z, acc[w].z); acc[w].w = fmaf(mv.x, w0.w, acc[w].w);
                acc[w].x = fmaf(mv.y, w1.x, acc[w].x); acc[w].y = fmaf(mv.y, w1.y, acc[w].y);
                acc[w].z = fmaf(mv.y, w1.z, acc[w].z); acc[w].w = fmaf(mv.y, w1.w, acc[w].w);
                acc[w].x = fmaf(mv.z, w2.x, acc[w].x); acc[w].y = fmaf(mv.z, w2.y, acc[w].y);
                acc[w].z = fmaf(mv.z, w2.z, acc[w].z); acc[w].w = fmaf(mv.z, w2.w, acc[w].w);
                acc[w].x = fmaf(mv.w, w3.x, acc[w].x); acc[w].y = fmaf(mv.w, w3.y, acc[w].y);
                acc[w].z = fmaf(mv.w, w3.z, acc[w].z); acc[w].w = fmaf(mv.w, w3.w, acc[w].w);
            }
        }
        __syncthreads();   // s_m4 reads done; also s_ps fully dead -> region A reusable
#pragma unroll
        for (int w = 0; w < NW; ++w) s_hp[(p * NW + w) * 16 + j4] = acc[w];
    }
    __syncthreads();

    // ================= Phase 2b: reduce 16 k-parts, +b1, softsign =================
    if (tid < NW * H) {
        const float* s_hpf = reinterpret_cast<const float*>(s_hp);
        const int w = tid >> 6;
        const int j = tid & 63;
        float s = b1[j];
#pragma unroll
        for (int p = 0; p < 16; ++p) s += s_hpf[(p * NW + w) * H + j];
        s_h[w][j] = s / (1.0f + fabsf(s));
    }
    __syncthreads();

    // ================= Phase 3: g_pre = h @ W2, 2-way j-split, batched =================
    // Thread = (q = tid>>7 j-part, d4 = tid&127). j in [q*32, q*32+32).
    {
        const float4* s_h4 = reinterpret_cast<const float4*>(&s_h[0][0]); // [NW][16]
        const int q  = tid >> 7;
        const int d4 = tid & 127;
        float4 acc[NW];
#pragma unroll
        for (int w = 0; w < NW; ++w) acc[w] = make_float4(0.f, 0.f, 0.f, 0.f);
#pragma unroll 2
        for (int jj4 = 0; jj4 < 8; ++jj4) {
            const int jg = q * 8 + jj4;                 // float4 group of j
            const int j  = jg * 4;
            const float4 w0 = W2f4[(size_t)(j + 0) * 128 + d4];
            const float4 w1 = W2f4[(size_t)(j + 1) * 128 + d4];
            const float4 w2 = W2f4[(size_t)(j + 2) * 128 + d4];
            const float4 w3 = W2f4[(size_t)(j + 3) * 128 + d4];
#pragma unroll
            for (int w = 0; w < NW; ++w) {
                const float4 hv = s_h4[w * 16 + jg];
                acc[w].x = fmaf(hv.x, w0.x, acc[w].x); acc[w].y = fmaf(hv.x, w0.y, acc[w].y);
                acc[w].z = fmaf(hv.x, w0.z, acc[w].z); acc[w].w = fmaf(hv.x, w0.w, acc[w].w);
                acc[w].x = fmaf(hv.y, w1.x, acc[w].x); acc[w].y = fmaf(hv.y, w1.y, acc[w].y);
                acc[w].z = fmaf(hv.y, w1.z, acc[w].z); acc[w].w = fmaf(hv.y, w1.w, acc[w].w);
                acc[w].x = fmaf(hv.z, w2.x, acc[w].x); acc[w].y = fmaf(hv.z, w2.y, acc[w].y);
                acc[w].z = fmaf(hv.z, w2.z, acc[w].z); acc[w].w = fmaf(hv.z, w2.w, acc[w].w);
                acc[w].x = fmaf(hv.w, w3.x, acc[w].x); acc[w].y = fmaf(hv.w, w3.y, acc[w].y);
                acc[w].z = fmaf(hv.w, w3.z, acc[w].z); acc[w].w = fmaf(hv.w, w3.w, acc[w].w);
            }
        }
        __syncthreads();   // s_hp reads (ph2b) done -> region A reusable as s_gp
#pragma unroll
        for (int w = 0; w < NW; ++w) s_gp[(q * NW + w) * 128 + d4] = acc[w];
    }
    __syncthreads();

    // ================= Phase 3b: reduce 2 j-parts, +b2, softsign, sigmoid =================
    {
        const int w  = tid >> 7;
        const int d4 = tid & 127;
        const float4 a  = s_gp[(0 * NW + w) * 128 + d4];
        const float4 b  = s_gp[(1 * NW + w) * 128 + d4];
        const float4 bb = b2f4[d4];
        float4 s;
        s.x = a.x + b.x + bb.x; s.y = a.y + b.y + bb.y;
        s.z = a.z + b.z + bb.z; s.w = a.w + b.w + bb.w;
        s.x = s.x / (1.0f + fabsf(s.x)); s.y = s.y / (1.0f + fabsf(s.y));
        s.z = s.z / (1.0f + fabsf(s.z)); s.w = s.w / (1.0f + fabsf(s.w));
        float4 g;
        g.x = 1.0f / (1.0f + __expf(-s.x)); g.y = 1.0f / (1.0f + __expf(-s.y));
        g.z = 1.0f / (1.0f + __expf(-s.z)); g.w = 1.0f / (1.0f + __expf(-s.w));
        __syncthreads();   // s_m4 reads (ph2) long done -> region B reusable as s_g4
        s_g4[w * 128 + d4] = g;
    }
    __syncthreads();

    // ================= Phase 4: gate from registers, store =================
    {
        const int c = tid & 127;
#pragma unroll
        for (int w = 0; w < NW; ++w) {
            const float4 g = s_g4[w * 128 + c];
#pragma unroll
            for (int i = 0; i < 8; ++i) {
                float4 o;
                o.x = r[w][i].x * g.x; o.y = r[w][i].y * g.y;
                o.z = r[w][i].z * g.z; o.w = r[w][i].w * g.w;
                yw[w * 2048 + i * TPB + tid] = o;
            }
        }
    }
}

extern "C" void kernel_launch(void* const* d_in, const int* in_sizes, int n_in,
                              void* d_out, int out_size, void* d_ws, size_t ws_size,
                              hipStream_t stream) {
    const float* x  = (const float*)d_in[0];
    const float* W1 = (const float*)d_in[1];
    const float* b1 = (const float*)d_in[2];
    const float* W2 = (const float*)d_in[3];
    const float* b2 = (const float*)d_in[4];
    float* y = (float*)d_out;

    const int n_windows = in_sizes[0] / (WIN * D);   // B * (M/WIN) = 4096
    const int n_blocks  = n_windows / NW;            // 2048
    se_block_kernel<<<dim3(n_blocks), dim3(TPB), 0, stream>>>(x, W1, b1, W2, b2, y);
}

// Round 8
// 85.123 us; speedup vs baseline: 1.3002x; 1.3002x over previous
//
#include <hip/hip_runtime.h>
#include <cmath>

// SE block: windowed mean-pool -> softsign(mW1+b1) -> sigmoid(softsign(hW2+b2)) -> gate x.
// B=32, M=2048, D=512, H=64, WIN=16 (M % WIN == 0, so reference edge-pad is a no-op).
// R7: two-kernel split. The fused kernel's serial phase chain is latency-bound at
//     4-5 blocks/CU (R4=56us) and every occupancy fix backfired (R5 FETCH x2, R6 spills).
//     Kernel A: gates for all windows -> d_ws (streaming x read, NW=4 amortizes weights).
//     Kernel B: y = x * g, grid-stride, nontemporal y stores (keep x L3-resident).
//     Fallback to the R4 fused kernel if ws_size < 8 MB.

constexpr int WIN = 16;
constexpr int D   = 512;
constexpr int H   = 64;
constexpr int TPB = 256;
constexpr int NWA = 4;                 // windows per block, gate kernel

typedef float v4f __attribute__((ext_vector_type(4)));

// ======================= Kernel A: gates =======================
__global__ __launch_bounds__(TPB) void se_gate_kernel(
    const float* __restrict__ x,
    const float* __restrict__ W1,
    const float* __restrict__ b1,
    const float* __restrict__ W2,
    const float* __restrict__ b2,
    float* __restrict__ g_out)        // [n_windows][D]
{
    const int tid = threadIdx.x;
    const size_t base = (size_t)blockIdx.x * (size_t)(NWA * WIN * D);
    const float4* __restrict__ xw = reinterpret_cast<const float4*>(x + base);

    const float4* __restrict__ W1f4 = reinterpret_cast<const float4*>(W1); // [512] rows x 16 f4
    const float4* __restrict__ W2f4 = reinterpret_cast<const float4*>(W2); // [64] rows x 128 f4
    const float4* __restrict__ b2f4 = reinterpret_cast<const float4*>(b2);

    // region A (16 KB): s_ps [NWA][256] f4 | s_hp [16][NWA][16] f4 | s_gp [2][NWA][128] f4
    // region B (8 KB):  s_m4 [NWA][128] f4
    __shared__ __align__(16) char sA[16 * 1024];
    __shared__ __align__(16) char sB[8 * 1024];
    __shared__ float s_h[NWA][H];

    float4* s_ps = reinterpret_cast<float4*>(sA);
    float4* s_hp = reinterpret_cast<float4*>(sA);
    float4* s_gp = reinterpret_cast<float4*>(sA);
    float4* s_m4 = reinterpret_cast<float4*>(sB);

    // ---- Phase 1: per-thread partial sums (streaming x read; 32 independent loads)
#pragma unroll
    for (int w = 0; w < NWA; ++w) {
        float4 ps = make_float4(0.f, 0.f, 0.f, 0.f);
#pragma unroll
        for (int i = 0; i < 8; ++i) {
            const float4 v = xw[w * 2048 + i * TPB + tid];
            ps.x += v.x; ps.y += v.y; ps.z += v.z; ps.w += v.w;
        }
        s_ps[w * TPB + tid] = ps;
    }
    __syncthreads();

    // ---- Phase 1b: window means (NWA*128 = 512 tasks over 256 threads)
#pragma unroll
    for (int rep = 0; rep < NWA * 128 / TPB; ++rep) {
        const int idx = rep * TPB + tid;
        const int w = idx >> 7;
        const int c = idx & 127;
        const float4 a = s_ps[w * TPB + c];
        const float4 b = s_ps[w * TPB + c + 128];
        const float sc = 1.0f / 16.0f;
        float4 m;
        m.x = (a.x + b.x) * sc; m.y = (a.y + b.y) * sc;
        m.z = (a.z + b.z) * sc; m.w = (a.w + b.w) * sc;
        s_m4[w * 128 + c] = m;
    }
    __syncthreads();

    // ---- Phase 2: h_pre = m @ W1, 16-way k-split, batched over NWA
    {
        const int p  = tid >> 4;
        const int j4 = tid & 15;
        float4 acc[NWA];
#pragma unroll
        for (int w = 0; w < NWA; ++w) acc[w] = make_float4(0.f, 0.f, 0.f, 0.f);
#pragma unroll 2
        for (int kk4 = 0; kk4 < 8; ++kk4) {
            const int c4 = p * 8 + kk4;
            const int k  = c4 * 4;
            const float4 w0 = W1f4[(size_t)(k + 0) * 16 + j4];
            const float4 w1 = W1f4[(size_t)(k + 1) * 16 + j4];
            const float4 w2 = W1f4[(size_t)(k + 2) * 16 + j4];
            const float4 w3 = W1f4[(size_t)(k + 3) * 16 + j4];
#pragma unroll
            for (int w = 0; w < NWA; ++w) {
                const float4 mv = s_m4[w * 128 + c4];
                acc[w].x = fmaf(mv.x, w0.x, acc[w].x); acc[w].y = fmaf(mv.x, w0.y, acc[w].y);
                acc[w].z = fmaf(mv.x, w0.z, acc[w].z); acc[w].w = fmaf(mv.x, w0.w, acc[w].w);
                acc[w].x = fmaf(mv.y, w1.x, acc[w].x); acc[w].y = fmaf(mv.y, w1.y, acc[w].y);
                acc[w].z = fmaf(mv.y, w1.z, acc[w].z); acc[w].w = fmaf(mv.y, w1.w, acc[w].w);
                acc[w].x = fmaf(mv.z, w2.x, acc[w].x); acc[w].y = fmaf(mv.z, w2.y, acc[w].y);
                acc[w].z = fmaf(mv.z, w2.z, acc[w].z); acc[w].w = fmaf(mv.z, w2.w, acc[w].w);
                acc[w].x = fmaf(mv.w, w3.x, acc[w].x); acc[w].y = fmaf(mv.w, w3.y, acc[w].y);
                acc[w].z = fmaf(mv.w, w3.z, acc[w].z); acc[w].w = fmaf(mv.w, w3.w, acc[w].w);
            }
        }
        __syncthreads();   // ph1b's s_ps reads done -> region A reusable as s_hp
#pragma unroll
        for (int w = 0; w < NWA; ++w) s_hp[(p * NWA + w) * 16 + j4] = acc[w];
    }
    __syncthreads();

    // ---- Phase 2b: reduce 16 k-parts, +b1, softsign (NWA*64 = 256 tasks)
    {
        const float* s_hpf = reinterpret_cast<const float*>(s_hp);
        const int w = tid >> 6;
        const int j = tid & 63;
        float s = b1[j];
#pragma unroll
        for (int p = 0; p < 16; ++p) s += s_hpf[(p * NWA + w) * H + j];
        s_h[w][j] = s / (1.0f + fabsf(s));
    }
    __syncthreads();

    // ---- Phase 3: g_pre = h @ W2, 2-way j-split, batched
    {
        const float4* s_h4 = reinterpret_cast<const float4*>(&s_h[0][0]); // [NWA][16]
        const int q  = tid >> 7;
        const int d4 = tid & 127;
        float4 acc[NWA];
#pragma unroll
        for (int w = 0; w < NWA; ++w) acc[w] = make_float4(0.f, 0.f, 0.f, 0.f);
#pragma unroll 2
        for (int jj4 = 0; jj4 < 8; ++jj4) {
            const int jg = q * 8 + jj4;
            const int j  = jg * 4;
            const float4 w0 = W2f4[(size_t)(j + 0) * 128 + d4];
            const float4 w1 = W2f4[(size_t)(j + 1) * 128 + d4];
            const float4 w2 = W2f4[(size_t)(j + 2) * 128 + d4];
            const float4 w3 = W2f4[(size_t)(j + 3) * 128 + d4];
#pragma unroll
            for (int w = 0; w < NWA; ++w) {
                const float4 hv = s_h4[w * 16 + jg];
                acc[w].x = fmaf(hv.x, w0.x, acc[w].x); acc[w].y = fmaf(hv.x, w0.y, acc[w].y);
                acc[w].z = fmaf(hv.x, w0.z, acc[w].z); acc[w].w = fmaf(hv.x, w0.w, acc[w].w);
                acc[w].x = fmaf(hv.y, w1.x, acc[w].x); acc[w].y = fmaf(hv.y, w1.y, acc[w].y);
                acc[w].z = fmaf(hv.y, w1.z, acc[w].z); acc[w].w = fmaf(hv.y, w1.w, acc[w].w);
                acc[w].x = fmaf(hv.z, w2.x, acc[w].x); acc[w].y = fmaf(hv.z, w2.y, acc[w].y);
                acc[w].z = fmaf(hv.z, w2.z, acc[w].z); acc[w].w = fmaf(hv.z, w2.w, acc[w].w);
                acc[w].x = fmaf(hv.w, w3.x, acc[w].x); acc[w].y = fmaf(hv.w, w3.y, acc[w].y);
                acc[w].z = fmaf(hv.w, w3.z, acc[w].z); acc[w].w = fmaf(hv.w, w3.w, acc[w].w);
            }
        }
        __syncthreads();   // ph2b's s_hp reads done -> region A reusable as s_gp
#pragma unroll
        for (int w = 0; w < NWA; ++w) s_gp[(q * NWA + w) * 128 + d4] = acc[w];
    }
    __syncthreads();

    // ---- Phase 3b: reduce 2 j-parts, +b2, softsign, sigmoid, store g (512 tasks)
    {
        float4* g4 = reinterpret_cast<float4*>(g_out) + (size_t)blockIdx.x * (NWA * 128);
#pragma unroll
        for (int rep = 0; rep < NWA * 128 / TPB; ++rep) {
            const int idx = rep * TPB + tid;
            const int w  = idx >> 7;
            const int d4 = idx & 127;
            const float4 a  = s_gp[(0 * NWA + w) * 128 + d4];
            const float4 b  = s_gp[(1 * NWA + w) * 128 + d4];
            const float4 bb = b2f4[d4];
            float4 s;
            s.x = a.x + b.x + bb.x; s.y = a.y + b.y + bb.y;
            s.z = a.z + b.z + bb.z; s.w = a.w + b.w + bb.w;
            s.x = s.x / (1.0f + fabsf(s.x)); s.y = s.y / (1.0f + fabsf(s.y));
            s.z = s.z / (1.0f + fabsf(s.z)); s.w = s.w / (1.0f + fabsf(s.w));
            float4 g;
            g.x = 1.0f / (1.0f + __expf(-s.x)); g.y = 1.0f / (1.0f + __expf(-s.y));
            g.z = 1.0f / (1.0f + __expf(-s.z)); g.w = 1.0f / (1.0f + __expf(-s.w));
            g4[w * 128 + d4] = g;
        }
    }
}

// ======================= Kernel B: apply =======================
__global__ __launch_bounds__(TPB) void se_apply_kernel(
    const float* __restrict__ x,
    const float* __restrict__ g,
    float* __restrict__ y,
    int n4)
{
    const float4* __restrict__ x4 = reinterpret_cast<const float4*>(x);
    const float4* __restrict__ g4 = reinterpret_cast<const float4*>(g);
    v4f*          __restrict__ y4 = reinterpret_cast<v4f*>(y);

    const int stride = gridDim.x * blockDim.x;
    for (int i = blockIdx.x * blockDim.x + threadIdx.x; i < n4; i += stride) {
        const float4 v  = x4[i];
        const float4 gg = g4[((i >> 11) << 7) | (i & 127)];  // window = i/2048, c4 = i&127
        v4f o;
        o.x = v.x * gg.x; o.y = v.y * gg.y; o.z = v.z * gg.z; o.w = v.w * gg.w;
        __builtin_nontemporal_store(o, &y4[i]);   // don't evict x from L3
    }
}

// ======================= Fallback: R4 fused (56.4 us) =======================
constexpr int NWF = 2;

__global__ __launch_bounds__(TPB, 4) void se_fused_kernel(
    const float* __restrict__ x,
    const float* __restrict__ W1,
    const float* __restrict__ b1,
    const float* __restrict__ W2,
    const float* __restrict__ b2,
    float* __restrict__ y)
{
    const int tid = threadIdx.x;
    const size_t base = (size_t)blockIdx.x * (size_t)(NWF * WIN * D);
    const float4* __restrict__ xw = reinterpret_cast<const float4*>(x + base);
    float4*       __restrict__ yw = reinterpret_cast<float4*>(y + base);

    const float4* __restrict__ W1f4 = reinterpret_cast<const float4*>(W1);
    const float4* __restrict__ W2f4 = reinterpret_cast<const float4*>(W2);
    const float4* __restrict__ b2f4 = reinterpret_cast<const float4*>(b2);

    __shared__ float4 s_ps[NWF][TPB];
    __shared__ float4 s_m4[NWF][D / 4];
    __shared__ float4 s_hp[16][NWF][H / 4];
    __shared__ float  s_h[NWF][H];
    __shared__ float4 s_gp[2][NWF][D / 4];
    __shared__ float4 s_g4[NWF][D / 4];

    float4 r[NWF][8];
#pragma unroll
    for (int w = 0; w < NWF; ++w)
#pragma unroll
        for (int i = 0; i < 8; ++i) r[w][i] = xw[w * 2048 + i * TPB + tid];

#pragma unroll
    for (int w = 0; w < NWF; ++w) {
        float4 ps = r[w][0];
#pragma unroll
        for (int i = 1; i < 8; ++i) {
            ps.x += r[w][i].x; ps.y += r[w][i].y; ps.z += r[w][i].z; ps.w += r[w][i].w;
        }
        s_ps[w][tid] = ps;
    }
    __syncthreads();
    {
        const int w = tid >> 7;
        const int c = tid & 127;
        const float4 a = s_ps[w][c];
        const float4 b = s_ps[w][c + 128];
        const float sc = 1.0f / 16.0f;
        float4 m;
        m.x = (a.x + b.x) * sc; m.y = (a.y + b.y) * sc;
        m.z = (a.z + b.z) * sc; m.w = (a.w + b.w) * sc;
        s_m4[w][c] = m;
    }
    __syncthreads();
    {
        const int p  = tid >> 4;
        const int j4 = tid & 15;
        float4 acc[NWF];
#pragma unroll
        for (int w = 0; w < NWF; ++w) acc[w] = make_float4(0.f, 0.f, 0.f, 0.f);
#pragma unroll 2
        for (int kk4 = 0; kk4 < 8; ++kk4) {
            const int c4 = p * 8 + kk4;
            const int k  = c4 * 4;
            const float4 w0 = W1f4[(size_t)(k + 0) * 16 + j4];
            const float4 w1 = W1f4[(size_t)(k + 1) * 16 + j4];
            const float4 w2 = W1f4[(size_t)(k + 2) * 16 + j4];
            const float4 w3 = W1f4[(size_t)(k + 3) * 16 + j4];
#pragma unroll
            for (int w = 0; w < NWF; ++w) {
                const float4 mv = s_m4[w][c4];
                acc[w].x = fmaf(mv.x, w0.x, acc[w].x); acc[w].y = fmaf(mv.x, w0.y, acc[w].y);
                acc[w].z = fmaf(mv.x, w0.z, acc[w].z); acc[w].w = fmaf(mv.x, w0.w, acc[w].w);
                acc[w].x = fmaf(mv.y, w1.x, acc[w].x); acc[w].y = fmaf(mv.y, w1.y, acc[w].y);
                acc[w].z = fmaf(mv.y, w1.z, acc[w].z); acc[w].w = fmaf(mv.y, w1.w, acc[w].w);
                acc[w].x = fmaf(mv.z, w2.x, acc[w].x); acc[w].y = fmaf(mv.z, w2.y, acc[w].y);
                acc[w].z = fmaf(mv.z, w2.z, acc[w].z); acc[w].w = fmaf(mv.z, w2.w, acc[w].w);
                acc[w].x = fmaf(mv.w, w3.x, acc[w].x); acc[w].y = fmaf(mv.w, w3.y, acc[w].y);
                acc[w].z = fmaf(mv.w, w3.z, acc[w].z); acc[w].w = fmaf(mv.w, w3.w, acc[w].w);
            }
        }
#pragma unroll
        for (int w = 0; w < NWF; ++w) s_hp[p][w][j4] = acc[w];
    }
    __syncthreads();
    if (tid < NWF * H) {
        const float* s_hpf = reinterpret_cast<const float*>(s_hp);
        const int w = tid >> 6;
        const int j = tid & 63;
        float s = b1[j];
#pragma unroll
        for (int p = 0; p < 16; ++p) s += s_hpf[(p * NWF + w) * H + j];
        s_h[w][j] = s / (1.0f + fabsf(s));
    }
    __syncthreads();
    {
        const float4* s_h4 = reinterpret_cast<const float4*>(&s_h[0][0]);
        const int q  = tid >> 7;
        const int d4 = tid & 127;
        float4 acc[NWF];
#pragma unroll
        for (int w = 0; w < NWF; ++w) acc[w] = make_float4(0.f, 0.f, 0.f, 0.f);
#pragma unroll 2
        for (int jj4 = 0; jj4 < 8; ++jj4) {
            const int jg = q * 8 + jj4;
            const int j  = jg * 4;
            const float4 w0 = W2f4[(size_t)(j + 0) * 128 + d4];
            const float4 w1 = W2f4[(size_t)(j + 1) * 128 + d4];
            const float4 w2 = W2f4[(size_t)(j + 2) * 128 + d4];
            const float4 w3 = W2f4[(size_t)(j + 3) * 128 + d4];
#pragma unroll
            for (int w = 0; w < NWF; ++w) {
                const float4 hv = s_h4[w * 16 + jg];
                acc[w].x = fmaf(hv.x, w0.x, acc[w].x); acc[w].y = fmaf(hv.x, w0.y, acc[w].y);
                acc[w].z = fmaf(hv.x, w0.z, acc[w].z); acc[w].w = fmaf(hv.x, w0.w, acc[w].w);
                acc[w].x = fmaf(hv.y, w1.x, acc[w].x); acc[w].y = fmaf(hv.y, w1.y, acc[w].y);
                acc[w].z = fmaf(hv.y, w1.z, acc[w].z); acc[w].w = fmaf(hv.y, w1.w, acc[w].w);
                acc[w].x = fmaf(hv.z, w2.x, acc[w].x); acc[w].y = fmaf(hv.z, w2.y, acc[w].y);
                acc[w].z = fmaf(hv.z, w2.z, acc[w].z); acc[w].w = fmaf(hv.z, w2.w, acc[w].w);
                acc[w].x = fmaf(hv.w, w3.x, acc[w].x); acc[w].y = fmaf(hv.w, w3.y, acc[w].y);
                acc[w].z = fmaf(hv.w, w3.z, acc[w].z); acc[w].w = fmaf(hv.w, w3.w, acc[w].w);
            }
        }
#pragma unroll
        for (int w = 0; w < NWF; ++w) s_gp[q][w][d4] = acc[w];
    }
    __syncthreads();
    {
        const int w  = tid >> 7;
        const int d4 = tid & 127;
        const float4 a  = s_gp[0][w][d4];
        const float4 b  = s_gp[1][w][d4];
        const float4 bb = b2f4[d4];
        float4 s;
        s.x = a.x + b.x + bb.x; s.y = a.y + b.y + bb.y;
        s.z = a.z + b.z + bb.z; s.w = a.w + b.w + bb.w;
        s.x = s.x / (1.0f + fabsf(s.x)); s.y = s.y / (1.0f + fabsf(s.y));
        s.z = s.z / (1.0f + fabsf(s.z)); s.w = s.w / (1.0f + fabsf(s.w));
        float4 g;
        g.x = 1.0f / (1.0f + __expf(-s.x)); g.y = 1.0f / (1.0f + __expf(-s.y));
        g.z = 1.0f / (1.0f + __expf(-s.z)); g.w = 1.0f / (1.0f + __expf(-s.w));
        s_g4[w][d4] = g;
    }
    __syncthreads();
    {
        const int c = tid & 127;
#pragma unroll
        for (int w = 0; w < NWF; ++w) {
            const float4 g = s_g4[w][c];
#pragma unroll
            for (int i = 0; i < 8; ++i) {
                float4 o;
                o.x = r[w][i].x * g.x; o.y = r[w][i].y * g.y;
                o.z = r[w][i].z * g.z; o.w = r[w][i].w * g.w;
                yw[w * 2048 + i * TPB + tid] = o;
            }
        }
    }
}

extern "C" void kernel_launch(void* const* d_in, const int* in_sizes, int n_in,
                              void* d_out, int out_size, void* d_ws, size_t ws_size,
                              hipStream_t stream) {
    const float* x  = (const float*)d_in[0];
    const float* W1 = (const float*)d_in[1];
    const float* b1 = (const float*)d_in[2];
    const float* W2 = (const float*)d_in[3];
    const float* b2 = (const float*)d_in[4];
    float* y = (float*)d_out;

    const int n_elems   = in_sizes[0];
    const int n_windows = n_elems / (WIN * D);          // 4096
    const size_t g_bytes = (size_t)n_windows * D * sizeof(float);  // 8 MB

    if (ws_size >= g_bytes) {
        float* g = (float*)d_ws;
        se_gate_kernel<<<dim3(n_windows / NWA), dim3(TPB), 0, stream>>>(x, W1, b1, W2, b2, g);
        const int n4 = n_elems / 4;
        se_apply_kernel<<<dim3(2048), dim3(TPB), 0, stream>>>(x, g, y, n4);
    } else {
        se_fused_kernel<<<dim3(n_windows / NWF), dim3(TPB), 0, stream>>>(x, W1, b1, W2, b2, y);
    }
}

// Round 9
// 62.347 us; speedup vs baseline: 1.7752x; 1.3653x over previous
//
#include <hip/hip_runtime.h>
#include <cmath>

// SE block: windowed mean-pool -> softsign(mW1+b1) -> sigmoid(softsign(hW2+b2)) -> gate x.
// B=32, M=2048, D=512, H=64, WIN=16 (M % WIN == 0, so reference edge-pad is a no-op).
// R8: latency attack on the R4 fused structure (56.4us best):
//  (1) raw barriers (lgkmcnt(0)+s_barrier) instead of __syncthreads — hipcc's
//      __syncthreads emits s_waitcnt vmcnt(0) which drains ALL global loads at every
//      barrier, killing any prefetch. All LDS traffic here is reg-sourced, so only
//      lgkmcnt ordering is required. Global-load value deps get their own compiler waits.
//  (2) persistent 8-window blocks (grid=512, exactly 2 blocks/CU), 4 groups x NW=2,
//      double-buffered register prefetch: next group's 32 x-loads issue right after the
//      current group's first barrier and retire under the matmul phases -> HBM stays busy.
//      vmcnt is FIFO: waiting on current-group values never drains the younger prefetch.

constexpr int WIN = 16;
constexpr int D   = 512;
constexpr int H   = 64;
constexpr int TPB = 256;
constexpr int NW  = 2;                    // windows per group
constexpr int NG  = 4;                    // groups per block (8 windows/block)
constexpr int GSTRIDE = NW * WIN * D / 4; // group stride in float4 = 4096

// LDS-only barrier: order LDS writes->reads across the workgroup WITHOUT draining vmcnt.
__device__ __forceinline__ void bar_lds() {
    asm volatile("s_waitcnt lgkmcnt(0)" ::: "memory");
    __builtin_amdgcn_s_barrier();
    asm volatile("" ::: "memory");        // keep later LDS ops from hoisting above barrier
}

__device__ __forceinline__ void load_group(const float4* __restrict__ xg, int tid,
                                           float4 r[NW][8]) {
#pragma unroll
    for (int w = 0; w < NW; ++w)
#pragma unroll
        for (int i = 0; i < 8; ++i)
            r[w][i] = xg[w * 2048 + i * TPB + tid];
}

// Process one group of NW windows held in r[][]; optionally prefetch the next group's x
// into rnext[][] right after the first barrier (so the loads fly under the matmul phases).
__device__ __forceinline__ void process_group(
    const float4 r[NW][8], float4 rnext[NW][8], const float4* __restrict__ xnext,
    float4* __restrict__ yg,
    const float4* __restrict__ W1f4, const float* __restrict__ b1,
    const float4* __restrict__ W2f4, const float4* __restrict__ b2f4,
    float4* __restrict__ sA, float4* __restrict__ s_g4, float* __restrict__ s_h,
    int tid)
{
    float4* s_ps = sA;   // [NW][256]      ph1 -> mm1 reads
    float4* s_hp = sA;   // [16][NW][16]   mm1 write -> ph2b read   (aliased, barrier-separated)
    float4* s_gp = sA;   // [2][NW][128]   mm2 write -> ph3b read   (aliased, barrier-separated)

    // ---- ph1: per-thread partial sums over this thread's 8 rows (col c = tid&127)
#pragma unroll
    for (int w = 0; w < NW; ++w) {
        float4 ps = r[w][0];
#pragma unroll
        for (int i = 1; i < 8; ++i) {
            ps.x += r[w][i].x; ps.y += r[w][i].y; ps.z += r[w][i].z; ps.w += r[w][i].w;
        }
        s_ps[w * TPB + tid] = ps;
    }
    bar_lds();                                  // B1

    // ---- prefetch next group's x (independent; retires under the phases below)
    if (xnext != nullptr) load_group(xnext, tid, rnext);

    // ---- mm1 (mean folded in): h_pre[j] = (1/16) sum_k (ps[k]+ps_pair[k]) W1[k][j]
    // Thread = (p = tid>>4 k-part, j4 = tid&15); k in [p*32, p*32+32).
    {
        const int p  = tid >> 4;
        const int j4 = tid & 15;
        float4 acc[NW];
#pragma unroll
        for (int w = 0; w < NW; ++w) acc[w] = make_float4(0.f, 0.f, 0.f, 0.f);
#pragma unroll 2
        for (int kk4 = 0; kk4 < 8; ++kk4) {
            const int c4 = p * 8 + kk4;
            const int k  = c4 * 4;
            const float4 w0 = W1f4[(size_t)(k + 0) * 16 + j4];
            const float4 w1 = W1f4[(size_t)(k + 1) * 16 + j4];
            const float4 w2 = W1f4[(size_t)(k + 2) * 16 + j4];
            const float4 w3 = W1f4[(size_t)(k + 3) * 16 + j4];
#pragma unroll
            for (int w = 0; w < NW; ++w) {
                const float4 a = s_ps[w * TPB + c4];
                const float4 b = s_ps[w * TPB + c4 + 128];
                const float mv0 = a.x + b.x, mv1 = a.y + b.y;
                const float mv2 = a.z + b.z, mv3 = a.w + b.w;
                acc[w].x = fmaf(mv0, w0.x, acc[w].x); acc[w].y = fmaf(mv0, w0.y, acc[w].y);
                acc[w].z = fmaf(mv0, w0.z, acc[w].z); acc[w].w = fmaf(mv0, w0.w, acc[w].w);
                acc[w].x = fmaf(mv1, w1.x, acc[w].x); acc[w].y = fmaf(mv1, w1.y, acc[w].y);
                acc[w].z = fmaf(mv1, w1.z, acc[w].z); acc[w].w = fmaf(mv1, w1.w, acc[w].w);
                acc[w].x = fmaf(mv2, w2.x, acc[w].x); acc[w].y = fmaf(mv2, w2.y, acc[w].y);
                acc[w].z = fmaf(mv2, w2.z, acc[w].z); acc[w].w = fmaf(mv2, w2.w, acc[w].w);
                acc[w].x = fmaf(mv3, w3.x, acc[w].x); acc[w].y = fmaf(mv3, w3.y, acc[w].y);
                acc[w].z = fmaf(mv3, w3.z, acc[w].z); acc[w].w = fmaf(mv3, w3.w, acc[w].w);
            }
        }
        bar_lds();                              // B2: all s_ps reads done before overwrite
        const float sc = 1.0f / 16.0f;
#pragma unroll
        for (int w = 0; w < NW; ++w) {
            float4 v = acc[w];
            v.x *= sc; v.y *= sc; v.z *= sc; v.w *= sc;
            s_hp[(p * NW + w) * 16 + j4] = v;
        }
    }
    bar_lds();                                  // B3

    // ---- ph2b: reduce 16 k-parts, +b1, softsign
    if (tid < NW * H) {
        const float* s_hpf = reinterpret_cast<const float*>(s_hp);
        const int w = tid >> 6;
        const int j = tid & 63;
        float s = b1[j];
#pragma unroll
        for (int p = 0; p < 16; ++p) s += s_hpf[(p * NW + w) * H + j];
        s_h[w * H + j] = s / (1.0f + fabsf(s));
    }
    bar_lds();                                  // B4

    // ---- mm2: g_pre[d] = sum_j h[j] W2[j][d]; thread = (q = tid>>7, d4 = tid&127)
    {
        const float4* s_h4 = reinterpret_cast<const float4*>(s_h);  // [NW][16]
        const int q  = tid >> 7;
        const int d4 = tid & 127;
        float4 acc[NW];
#pragma unroll
        for (int w = 0; w < NW; ++w) acc[w] = make_float4(0.f, 0.f, 0.f, 0.f);
#pragma unroll 2
        for (int jj4 = 0; jj4 < 8; ++jj4) {
            const int jg = q * 8 + jj4;
            const int j  = jg * 4;
            const float4 w0 = W2f4[(size_t)(j + 0) * 128 + d4];
            const float4 w1 = W2f4[(size_t)(j + 1) * 128 + d4];
            const float4 w2 = W2f4[(size_t)(j + 2) * 128 + d4];
            const float4 w3 = W2f4[(size_t)(j + 3) * 128 + d4];
#pragma unroll
            for (int w = 0; w < NW; ++w) {
                const float4 hv = s_h4[w * 16 + jg];
                acc[w].x = fmaf(hv.x, w0.x, acc[w].x); acc[w].y = fmaf(hv.x, w0.y, acc[w].y);
                acc[w].z = fmaf(hv.x, w0.z, acc[w].z); acc[w].w = fmaf(hv.x, w0.w, acc[w].w);
                acc[w].x = fmaf(hv.y, w1.x, acc[w].x); acc[w].y = fmaf(hv.y, w1.y, acc[w].y);
                acc[w].z = fmaf(hv.y, w1.z, acc[w].z); acc[w].w = fmaf(hv.y, w1.w, acc[w].w);
                acc[w].x = fmaf(hv.z, w2.x, acc[w].x); acc[w].y = fmaf(hv.z, w2.y, acc[w].y);
                acc[w].z = fmaf(hv.z, w2.z, acc[w].z); acc[w].w = fmaf(hv.z, w2.w, acc[w].w);
                acc[w].x = fmaf(hv.w, w3.x, acc[w].x); acc[w].y = fmaf(hv.w, w3.y, acc[w].y);
                acc[w].z = fmaf(hv.w, w3.z, acc[w].z); acc[w].w = fmaf(hv.w, w3.w, acc[w].w);
            }
        }
        // s_hp reads finished at B4 -> safe to overwrite region A as s_gp
#pragma unroll
        for (int w = 0; w < NW; ++w) s_gp[(q * NW + w) * 128 + d4] = acc[w];
    }
    bar_lds();                                  // B5

    // ---- ph3b: reduce 2 j-parts, +b2, softsign, sigmoid -> s_g4
    {
        const int w  = tid >> 7;
        const int d4 = tid & 127;
        const float4 a  = s_gp[(0 * NW + w) * 128 + d4];
        const float4 b  = s_gp[(1 * NW + w) * 128 + d4];
        const float4 bb = b2f4[d4];
        float4 s;
        s.x = a.x + b.x + bb.x; s.y = a.y + b.y + bb.y;
        s.z = a.z + b.z + bb.z; s.w = a.w + b.w + bb.w;
        s.x = s.x / (1.0f + fabsf(s.x)); s.y = s.y / (1.0f + fabsf(s.y));
        s.z = s.z / (1.0f + fabsf(s.z)); s.w = s.w / (1.0f + fabsf(s.w));
        float4 g;
        g.x = 1.0f / (1.0f + __expf(-s.x)); g.y = 1.0f / (1.0f + __expf(-s.y));
        g.z = 1.0f / (1.0f + __expf(-s.z)); g.w = 1.0f / (1.0f + __expf(-s.w));
        s_g4[w * 128 + d4] = g;
    }
    bar_lds();                                  // B6

    // ---- ph4: gate from registers, store. (next group's B1 orders s_g4 vs next writes)
    {
        const int c = tid & 127;
#pragma unroll
        for (int w = 0; w < NW; ++w) {
            const float4 g = s_g4[w * 128 + c];
#pragma unroll
            for (int i = 0; i < 8; ++i) {
                float4 o;
                o.x = r[w][i].x * g.x; o.y = r[w][i].y * g.y;
                o.z = r[w][i].z * g.z; o.w = r[w][i].w * g.w;
                yg[w * 2048 + i * TPB + tid] = o;
            }
        }
    }
}

__global__ __launch_bounds__(TPB, 2) void se_persist_kernel(
    const float* __restrict__ x,
    const float* __restrict__ W1,
    const float* __restrict__ b1,
    const float* __restrict__ W2,
    const float* __restrict__ b2,
    float* __restrict__ y)
{
    const int tid = threadIdx.x;
    const size_t base = (size_t)blockIdx.x * (size_t)(NG * NW * WIN * D);
    const float4* __restrict__ xw = reinterpret_cast<const float4*>(x + base);
    float4*       __restrict__ yw = reinterpret_cast<float4*>(y + base);

    const float4* __restrict__ W1f4 = reinterpret_cast<const float4*>(W1); // [512] x 16 f4
    const float4* __restrict__ W2f4 = reinterpret_cast<const float4*>(W2); // [64] x 128 f4
    const float4* __restrict__ b2f4 = reinterpret_cast<const float4*>(b2);

    __shared__ __align__(16) float4 sA[NW * TPB];     // 8 KB (s_ps | s_hp | s_gp)
    __shared__ __align__(16) float4 s_g4[NW * 128];   // 4 KB
    __shared__ float s_h[NW * H];                     // 512 B

    float4 rA[NW][8], rB[NW][8];

    load_group(xw, tid, rA);
    process_group(rA, rB, xw + 1 * GSTRIDE, yw,
                  W1f4, b1, W2f4, b2f4, sA, s_g4, s_h, tid);
    process_group(rB, rA, xw + 2 * GSTRIDE, yw + 1 * GSTRIDE,
                  W1f4, b1, W2f4, b2f4, sA, s_g4, s_h, tid);
    process_group(rA, rB, xw + 3 * GSTRIDE, yw + 2 * GSTRIDE,
                  W1f4, b1, W2f4, b2f4, sA, s_g4, s_h, tid);
    process_group(rB, rA, nullptr, yw + 3 * GSTRIDE,
                  W1f4, b1, W2f4, b2f4, sA, s_g4, s_h, tid);
}

extern "C" void kernel_launch(void* const* d_in, const int* in_sizes, int n_in,
                              void* d_out, int out_size, void* d_ws, size_t ws_size,
                              hipStream_t stream) {
    const float* x  = (const float*)d_in[0];
    const float* W1 = (const float*)d_in[1];
    const float* b1 = (const float*)d_in[2];
    const float* W2 = (const float*)d_in[3];
    const float* b2 = (const float*)d_in[4];
    float* y = (float*)d_out;

    const int n_windows = in_sizes[0] / (WIN * D);    // 4096
    const int n_blocks  = n_windows / (NG * NW);      // 512  (exactly 2 blocks/CU)
    se_persist_kernel<<<dim3(n_blocks), dim3(TPB), 0, stream>>>(x, W1, b1, W2, b2, y);
}